// Round 1
// baseline (1596.412 us; speedup 1.0000x reference)
//
#include <hip/hip_runtime.h>
#include <math.h>

// AxialAttentionBlock on gfx950.
// Pipeline (all bf16 MFMA GEMMs, pixel-major [p=B*H*W, c] activations):
//  stats1 -> stage1(transpose+scale) -> GEMM qkv -> LN(q,k) -> attn(row) -> attn(col)
//  -> stats2 -> stage2 -> GEMM outproj (+gamma_att*.. + x residual, epilogue) -> x3
//  -> 4x { GEMM mlp1+GELU -> GEMM mlp2 } -> stats3 -> final(transpose back)
// gammas are 1e-6 so output ~= x + bf16 rounding; tolerance 0.108 absolute.

typedef unsigned short u16;
typedef short bf16x8 __attribute__((ext_vector_type(8)));
typedef float f32x4 __attribute__((ext_vector_type(4)));

#define DEV static __device__ __forceinline__

DEV u16 f2bf(float f) {
    unsigned int u = __float_as_uint(f);
    u += 0x7fffu + ((u >> 16) & 1u);   // RTN-even
    return (u16)(u >> 16);
}
DEV float bf2f(u16 h) { return __uint_as_float(((unsigned int)h) << 16); }

// async global->LDS, 16B per lane; lds base must be wave-uniform (HW adds lane*16)
#define GLD16(gp, lp) __builtin_amdgcn_global_load_lds( \
    (const __attribute__((address_space(1))) unsigned int*)(const void*)(gp), \
    (__attribute__((address_space(3))) unsigned int*)(void*)(lp), 16, 0, 0)

#define MFMA16(a, b, c) __builtin_amdgcn_mfma_f32_16x16x32_bf16((a), (b), (c), 0, 0, 0)

// ---------------------------------------------------------------------------
// small prep kernels
// ---------------------------------------------------------------------------
__global__ void wcvt_kernel(const float* __restrict__ in, u16* __restrict__ out, int n) {
    int i = blockIdx.x * 256 + threadIdx.x;
    if (i < n) out[i] = f2bf(in[i]);
}

// fp32 [R][C] -> bf16 [C][R]
__global__ void wtrans_kernel(const float* __restrict__ in, u16* __restrict__ out, int R, int C) {
    __shared__ float tile[64][65];
    int r0 = blockIdx.x * 64, c0 = blockIdx.y * 64;
    for (int idx = threadIdx.x; idx < 4096; idx += 256) {
        int rr = idx >> 6, cc = idx & 63;
        tile[rr][cc] = in[(size_t)(r0 + rr) * C + c0 + cc];
    }
    __syncthreads();
    for (int idx = threadIdx.x; idx < 4096; idx += 256) {
        int cc = idx >> 6, rr = idx & 63;
        out[(size_t)(c0 + cc) * R + r0 + rr] = f2bf(tile[rr][cc]);
    }
}

// T5 relative bias table: biasT[head][i][j], L=128 for both axes
__global__ void bias_kernel(const float* __restrict__ emb, float* __restrict__ biasT) {
    int head = blockIdx.x, i = blockIdx.y, j = threadIdx.x;
    int rp = j - i;
    int ret = rp > 0 ? 16 : 0;
    int arp = rp < 0 ? -rp : rp;
    int bucket;
    if (arp < 8) bucket = ret + arp;
    else {
        int vl = 8 + (int)(logf((float)arp * 0.125f) * (8.0f / logf(16.0f)));
        if (vl > 15) vl = 15;
        bucket = ret + vl;
    }
    biasT[head * 16384 + i * 128 + j] = emb[bucket * 12 + head];
}

// per-(b,c) spatial std over contiguous x[b,c,:,:] -> s1 = w/(std+1e-8)
__global__ __launch_bounds__(256) void stats1_kernel(const float* __restrict__ x,
                                                     const float* __restrict__ w,
                                                     float* __restrict__ s1) {
    int bc = blockIdx.x;
    const f32x4* p = (const f32x4*)(x + (size_t)bc * 16384);
    float s = 0.f, sq = 0.f;
    for (int i = threadIdx.x; i < 4096; i += 256) {
        f32x4 v = p[i];
        s  += v[0] + v[1] + v[2] + v[3];
        sq += v[0]*v[0] + v[1]*v[1] + v[2]*v[2] + v[3]*v[3];
    }
    for (int d = 1; d < 64; d <<= 1) { s += __shfl_xor(s, d); sq += __shfl_xor(sq, d); }
    __shared__ float rs[4], rq[4];
    int wave = threadIdx.x >> 6;
    if ((threadIdx.x & 63) == 0) { rs[wave] = s; rq[wave] = sq; }
    __syncthreads();
    if (threadIdx.x == 0) {
        float S = rs[0] + rs[1] + rs[2] + rs[3];
        float Q = rq[0] + rq[1] + rq[2] + rq[3];
        float var = (Q - S * S * (1.0f / 16384.0f)) * (1.0f / 16383.0f);
        s1[bc] = w[bc % 768] / (sqrtf(var) + 1e-8f);
    }
}

// x [B,C,H,W] * s1 -> xn1 bf16 [p, c] (LDS transpose)
__global__ __launch_bounds__(256) void stage1_kernel(const float* __restrict__ x,
                                                     const float* __restrict__ s1,
                                                     u16* __restrict__ xn1) {
    __shared__ float tile[64][65];
    int hw0 = blockIdx.x * 64, c0 = blockIdx.y * 64, b = blockIdx.z;
    for (int idx = threadIdx.x; idx < 4096; idx += 256) {
        int cc = idx >> 6, ww = idx & 63;
        tile[cc][ww] = x[((size_t)(b * 768 + c0 + cc)) * 16384 + hw0 + ww] * s1[b * 768 + c0 + cc];
    }
    __syncthreads();
    for (int idx = threadIdx.x; idx < 4096; idx += 256) {
        int ww = idx >> 6, cc = idx & 63;
        xn1[((size_t)(b * 16384 + hw0 + ww)) * 768 + c0 + cc] = f2bf(tile[cc][ww]);
    }
}

// ---------------------------------------------------------------------------
// MFMA GEMM: C[M,N] = A[M,K] * Bw[N,K]^T (+epilogue); 128x128 tile, BK=64
// MODE 0: outb = bf16(acc + bias)                       (qkv proj)
// MODE 1: outb = bf16((acc+bias)*gamma[col] + x[b,col,hw])  (out proj + residual)
// MODE 2: outb = bf16(gelu(acc + bias))                 (mlp1)
// MODE 3: outb = bf16(acc + bias)                       (mlp2)
// ---------------------------------------------------------------------------
template <int MODE>
__global__ __launch_bounds__(256) void gemm_bt(const u16* __restrict__ A,
                                               const u16* __restrict__ Bw, int K,
                                               u16* __restrict__ outb,
                                               const float* __restrict__ bias,
                                               const float* __restrict__ gamma,
                                               const float* __restrict__ xres, int ldc) {
    __shared__ __align__(16) u16 As[8192];
    __shared__ __align__(16) u16 Bs[8192];
    const int tid = threadIdx.x;
    const int wave = tid >> 6, lane = tid & 63;
    const int ln = lane & 15, lq = lane >> 4;
    const int m0 = blockIdx.x * 128, n0 = blockIdx.y * 128;
    const int wm = (wave >> 1) * 64, wn = (wave & 1) * 64;
    const u16* Ag = A + (size_t)m0 * K;
    const u16* Bg = Bw + (size_t)n0 * K;
    const int srow = lane >> 3;          // 0..7
    const int scol = (lane & 7) * 8;     // 0,8,..,56
    f32x4 acc[4][4] = {};

    for (int k0 = 0; k0 < K; k0 += 64) {
        if (k0) __syncthreads();
#pragma unroll
        for (int r = 0; r < 4; r++) {
            int s = r * 4 + wave;                 // 0..15, wave-uniform
            int row = s * 8 + srow;               // 0..127
            GLD16(Ag + (size_t)row * K + k0 + scol, As + s * 512);
            GLD16(Bg + (size_t)row * K + k0 + scol, Bs + s * 512);
        }
        __syncthreads();
#pragma unroll
        for (int ks = 0; ks < 64; ks += 32) {
            const int ko = ks + lq * 8;
            bf16x8 af[4], bfr[4];
#pragma unroll
            for (int i = 0; i < 4; i++) af[i] = *(const bf16x8*)&As[(wm + i * 16 + ln) * 64 + ko];
#pragma unroll
            for (int j = 0; j < 4; j++) bfr[j] = *(const bf16x8*)&Bs[(wn + j * 16 + ln) * 64 + ko];
#pragma unroll
            for (int i = 0; i < 4; i++)
#pragma unroll
                for (int j = 0; j < 4; j++)
                    acc[i][j] = MFMA16(af[i], bfr[j], acc[i][j]);
        }
    }

#pragma unroll
    for (int i = 0; i < 4; i++) {
        const int row0 = m0 + wm + i * 16 + lq * 4;
#pragma unroll
        for (int j = 0; j < 4; j++) {
            const int col = n0 + wn + j * 16 + ln;
            const float bv = bias[col];
            if (MODE == 1) {
                const f32x4 xv = *(const f32x4*)&xres[((size_t)(row0 >> 14) * 768 + col) * 16384 + (row0 & 16383)];
                const float gv = gamma[col];
#pragma unroll
                for (int rg = 0; rg < 4; rg++) {
                    float val = (acc[i][j][rg] + bv) * gv + xv[rg];
                    outb[(size_t)(row0 + rg) * ldc + col] = f2bf(val);
                }
            } else if (MODE == 2) {
#pragma unroll
                for (int rg = 0; rg < 4; rg++) {
                    float val = acc[i][j][rg] + bv;
                    val = 0.5f * val * (1.0f + erff(val * 0.70710678f));
                    outb[(size_t)(row0 + rg) * ldc + col] = f2bf(val);
                }
            } else {
#pragma unroll
                for (int rg = 0; rg < 4; rg++)
                    outb[(size_t)(row0 + rg) * ldc + col] = f2bf(acc[i][j][rg] + bv);
            }
        }
    }
}

// ---------------------------------------------------------------------------
// LayerNorm over hd=64 for q and k slices of qkv [p, 2304], in place
// ---------------------------------------------------------------------------
__global__ __launch_bounds__(256) void lnqk_kernel(u16* __restrict__ qkv,
                                                   const float* __restrict__ qn_w,
                                                   const float* __restrict__ qn_b,
                                                   const float* __restrict__ kn_w,
                                                   const float* __restrict__ kn_b) {
    const int t = threadIdx.x, lane = t & 63;
    const int unit = blockIdx.x * 4 + (t >> 6);
    const int p = unit / 24;
    const int rr = unit % 24;
    const int head = rr >> 1, qk = rr & 1;
    const size_t base = (size_t)p * 2304 + head * 192 + qk * 64;
    float v = bf2f(qkv[base + lane]);
    float s = v;
#pragma unroll
    for (int d = 1; d < 64; d <<= 1) s += __shfl_xor(s, d);
    const float mean = s * (1.0f / 64.0f);
    const float dv = v - mean;
    float q2 = dv * dv;
#pragma unroll
    for (int d = 1; d < 64; d <<= 1) q2 += __shfl_xor(q2, d);
    const float rstd = rsqrtf(q2 * (1.0f / 64.0f) + 1e-5f);
    const float wv = qk ? kn_w[lane] : qn_w[lane];
    const float bv = qk ? kn_b[lane] : qn_b[lane];
    qkv[base + lane] = f2bf(dv * rstd * wv + bv);
}

// ---------------------------------------------------------------------------
// axial attention, one block per (b, pos, head); L=128, hd=64
// mode 0 (row, seq along W): att = 0.5*O ; mode 1 (col, seq along H): att += 0.5*O
// ---------------------------------------------------------------------------
__global__ __launch_bounds__(256) void attn_kernel(const u16* __restrict__ qkv,
                                                   u16* __restrict__ att,
                                                   const float* __restrict__ biasT,
                                                   const int mode) {
    __shared__ __align__(16) u16 sh[24576];   // 48 KB
    u16* Qs = sh;            // [128][64]
    u16* Ks = sh + 8192;     // [128][64]
    u16* Vt = sh + 16384;    // [64][128] (transposed)
    u16* Ps = sh;            // [128][128] overlays Q+K after barrier

    const int t = threadIdx.x, lane = t & 63, wave = t >> 6;
    const int ln = lane & 15, lq = lane >> 4;
    const int head = blockIdx.x % 12;
    const int bp = blockIdx.x / 12;
    const int pos = bp & 127, b = bp >> 7;

    for (int idx = t; idx < 2048; idx += 256) {
        const int i = idx >> 4, c4 = (idx & 15) * 4;
        const size_t p = (mode == 0) ? (size_t)(b * 16384 + pos * 128 + i)
                                     : (size_t)(b * 16384 + i * 128 + pos);
        const u16* src = qkv + p * 2304 + head * 192;
        union { uint2 u; u16 us[4]; } vv;
        *(uint2*)&Qs[i * 64 + c4] = *(const uint2*)(src + c4);
        *(uint2*)&Ks[i * 64 + c4] = *(const uint2*)(src + 64 + c4);
        vv.u = *(const uint2*)(src + 128 + c4);
#pragma unroll
        for (int q = 0; q < 4; q++) Vt[(c4 + q) * 128 + i] = vv.us[q];
    }
    __syncthreads();

    const int wr = wave * 32;
    f32x4 S[2][8] = {};
#pragma unroll
    for (int ks = 0; ks < 64; ks += 32) {
        const int ko = ks + lq * 8;
        bf16x8 aq[2];
#pragma unroll
        for (int i = 0; i < 2; i++) aq[i] = *(const bf16x8*)&Qs[(wr + i * 16 + ln) * 64 + ko];
#pragma unroll
        for (int j = 0; j < 8; j++) {
            const bf16x8 bk = *(const bf16x8*)&Ks[(j * 16 + ln) * 64 + ko];
            S[0][j] = MFMA16(aq[0], bk, S[0][j]);
            S[1][j] = MFMA16(aq[1], bk, S[1][j]);
        }
    }
    __syncthreads();   // all waves done reading Q/K before Ps overlays them

    float rowsum[2][4];
    const float* bp2 = biasT + head * 16384;
#pragma unroll
    for (int i = 0; i < 2; i++) {
#pragma unroll
        for (int rg = 0; rg < 4; rg++) {
            const int r = wr + i * 16 + lq * 4 + rg;
            float v[8];
            float mx = -1e30f;
#pragma unroll
            for (int j = 0; j < 8; j++) {
                v[j] = S[i][j][rg] * 0.125f + bp2[r * 128 + j * 16 + ln];
                mx = fmaxf(mx, v[j]);
            }
#pragma unroll
            for (int d = 1; d < 16; d <<= 1) mx = fmaxf(mx, __shfl_xor(mx, d));
            float sm = 0.f;
#pragma unroll
            for (int j = 0; j < 8; j++) { v[j] = __expf(v[j] - mx); sm += v[j]; }
#pragma unroll
            for (int d = 1; d < 16; d <<= 1) sm += __shfl_xor(sm, d);
            rowsum[i][rg] = sm;
#pragma unroll
            for (int j = 0; j < 8; j++) Ps[r * 128 + j * 16 + ln] = f2bf(v[j]);
        }
    }
    __syncthreads();

    f32x4 O[2][4] = {};
#pragma unroll
    for (int ks = 0; ks < 128; ks += 32) {
        const int ko = ks + lq * 8;
        bf16x8 ap[2];
#pragma unroll
        for (int i = 0; i < 2; i++) ap[i] = *(const bf16x8*)&Ps[(wr + i * 16 + ln) * 128 + ko];
#pragma unroll
        for (int j = 0; j < 4; j++) {
            const bf16x8 bv = *(const bf16x8*)&Vt[(j * 16 + ln) * 128 + ko];
            O[0][j] = MFMA16(ap[0], bv, O[0][j]);
            O[1][j] = MFMA16(ap[1], bv, O[1][j]);
        }
    }

#pragma unroll
    for (int i = 0; i < 2; i++) {
#pragma unroll
        for (int j = 0; j < 4; j++) {
#pragma unroll
            for (int rg = 0; rg < 4; rg++) {
                const int r = wr + i * 16 + lq * 4 + rg;
                const int d = j * 16 + ln;
                const float val = O[i][j][rg] / rowsum[i][rg] * 0.5f;
                const size_t p = (mode == 0) ? (size_t)(b * 16384 + pos * 128 + r)
                                             : (size_t)(b * 16384 + r * 128 + pos);
                const size_t a = p * 768 + head * 64 + d;
                if (mode == 0) att[a] = f2bf(val);
                else           att[a] = f2bf(bf2f(att[a]) + val);
            }
        }
    }
}

// ---------------------------------------------------------------------------
// per-(b,c) stats for pixel-major bf16 [p, 768]: partial sums, then finalize
// ---------------------------------------------------------------------------
__global__ __launch_bounds__(256) void statspm_kernel(const u16* __restrict__ in,
                                                      float* __restrict__ part) {
    const int c = blockIdx.y * 64 + (threadIdx.x & 63);
    const int g = threadIdx.x >> 6;
    const int b = blockIdx.z;
    const int rend = blockIdx.x * 1024 + 1024;
    float s = 0.f, sq = 0.f;
    for (int r = blockIdx.x * 1024 + g; r < rend; r += 4) {
        float v = bf2f(in[((size_t)(b * 16384 + r)) * 768 + c]);
        s += v; sq += v * v;
    }
    __shared__ float ls[4][64], lqq[4][64];
    ls[g][threadIdx.x & 63] = s;
    lqq[g][threadIdx.x & 63] = sq;
    __syncthreads();
    if (threadIdx.x < 64) {
        float S = ls[0][threadIdx.x] + ls[1][threadIdx.x] + ls[2][threadIdx.x] + ls[3][threadIdx.x];
        float Q = lqq[0][threadIdx.x] + lqq[1][threadIdx.x] + lqq[2][threadIdx.x] + lqq[3][threadIdx.x];
        size_t idx = ((size_t)(b * 768 + blockIdx.y * 64 + threadIdx.x) * 16 + blockIdx.x) * 2;
        part[idx] = S;
        part[idx + 1] = Q;
    }
}

__global__ void statsfin_kernel(const float* __restrict__ part, const float* __restrict__ w,
                                float* __restrict__ sc) {
    int i = blockIdx.x * 256 + threadIdx.x;   // 0..1535 = b*768+c
    if (i < 1536) {
        float S = 0.f, Q = 0.f;
        for (int k = 0; k < 16; k++) { S += part[(i * 16 + k) * 2]; Q += part[(i * 16 + k) * 2 + 1]; }
        float var = (Q - S * S * (1.0f / 16384.0f)) * (1.0f / 16383.0f);
        sc[i] = w[i % 768] / (sqrtf(var) + 1e-8f);
    }
}

__global__ __launch_bounds__(256) void stage2_kernel(const u16* __restrict__ att,
                                                     const float* __restrict__ s2,
                                                     u16* __restrict__ xn2) {
    const int p = blockIdx.x;
    const int b = p >> 14;
    const size_t base = (size_t)p * 768;
    for (int c = threadIdx.x; c < 768; c += 256)
        xn2[base + c] = f2bf(bf2f(att[base + c]) * s2[b * 768 + c]);
}

// out[b,c,hw] = x3[p,c] + gamma_mlp[c]*(h2[p,c]*s3[b,c]); transpose back to NCHW
__global__ __launch_bounds__(256) void final_kernel(const u16* __restrict__ x3,
                                                    const u16* __restrict__ h2,
                                                    const float* __restrict__ s3,
                                                    const float* __restrict__ gmlp,
                                                    float* __restrict__ out) {
    __shared__ float tile[64][65];
    int hw0 = blockIdx.x * 64, c0 = blockIdx.y * 64, b = blockIdx.z;
    for (int idx = threadIdx.x; idx < 4096; idx += 256) {
        int ww = idx >> 6, cc = idx & 63;
        int c = c0 + cc;
        size_t pp = ((size_t)(b * 16384 + hw0 + ww)) * 768 + c;
        tile[ww][cc] = bf2f(x3[pp]) + gmlp[c] * (bf2f(h2[pp]) * s3[b * 768 + c]);
    }
    __syncthreads();
    for (int idx = threadIdx.x; idx < 4096; idx += 256) {
        int cc = idx >> 6, ww = idx & 63;
        out[((size_t)(b * 768 + c0 + cc)) * 16384 + hw0 + ww] = tile[ww][cc];
    }
}

// ---------------------------------------------------------------------------
extern "C" void kernel_launch(void* const* d_in, const int* in_sizes, int n_in,
                              void* d_out, int out_size, void* d_ws, size_t ws_size,
                              hipStream_t stream) {
    (void)in_sizes; (void)n_in; (void)out_size;
    const float* x         = (const float*)d_in[0];
    const float* norm1_w   = (const float*)d_in[2];
    const float* norm2_w   = (const float*)d_in[3];
    const float* mlpnorm_w = (const float*)d_in[4];
    const float* gamma_att = (const float*)d_in[5];
    const float* gamma_mlp = (const float*)d_in[6];
    const float* in_w      = (const float*)d_in[7];
    const float* in_b      = (const float*)d_in[8];
    const float* out_w     = (const float*)d_in[9];
    const float* out_b     = (const float*)d_in[10];
    const float* qn_w      = (const float*)d_in[11];
    const float* qn_b      = (const float*)d_in[12];
    const float* kn_w      = (const float*)d_in[13];
    const float* kn_b      = (const float*)d_in[14];
    const float* emb       = (const float*)d_in[15];
    const float* w1        = (const float*)d_in[16];
    const float* b1        = (const float*)d_in[17];
    const float* w2        = (const float*)d_in[18];
    const float* b2        = (const float*)d_in[19];
    float* out = (float*)d_out;

    char* ws = (char*)d_ws;
    // region map (bytes); qkv region reused by xn2/x3/h2 after attention
    u16*   qkv   = (u16*)(ws + 0);            // 150,994,944
    u16*   xn2   = (u16*)(ws + 0);            //  50,331,648 (reuse)
    u16*   x3    = (u16*)(ws + 50331648);     //  50,331,648 (reuse)
    u16*   h2    = (u16*)(ws + 100663296);    //  50,331,648 (reuse)
    u16*   xn1   = (u16*)(ws + 150994944);    //  50,331,648 (then att)
    u16*   att   = (u16*)(ws + 150994944);
    u16*   h1b   = (u16*)(ws + 201326592);    //  50,331,648 (chunk buffer)
    u16*   winb  = (u16*)(ws + 251658240);    //   3,538,944
    u16*   woutb = (u16*)(ws + 255197184);    //   1,179,648
    u16*   w1t   = (u16*)(ws + 256376832);    //   4,718,592
    u16*   w2t   = (u16*)(ws + 261095424);    //   4,718,592
    float* biasT = (float*)(ws + 265814016);  //     786,432
    float* s1    = (float*)(ws + 266600448);
    float* s2    = (float*)(ws + 266606592);
    float* s3    = (float*)(ws + 266612736);
    float* part  = (float*)(ws + 266618880);  //     786,432
    if (ws_size < 267405312) return;          // insufficient workspace

    // weight prep (every launch; no static state allowed)
    wcvt_kernel<<<6912, 256, 0, stream>>>(in_w, winb, 2304 * 768);
    wcvt_kernel<<<2304, 256, 0, stream>>>(out_w, woutb, 768 * 768);
    wtrans_kernel<<<dim3(12, 48), 256, 0, stream>>>(w1, w1t, 768, 3072);
    wtrans_kernel<<<dim3(48, 12), 256, 0, stream>>>(w2, w2t, 3072, 768);
    bias_kernel<<<dim3(12, 128), 128, 0, stream>>>(emb, biasT);

    // norm1 + qkv projection
    stats1_kernel<<<1536, 256, 0, stream>>>(x, norm1_w, s1);
    stage1_kernel<<<dim3(256, 12, 2), 256, 0, stream>>>(x, s1, xn1);
    gemm_bt<0><<<dim3(256, 18), 256, 0, stream>>>(xn1, winb, 768, qkv, in_b, nullptr, nullptr, 2304);
    lnqk_kernel<<<196608, 256, 0, stream>>>(qkv, qn_w, qn_b, kn_w, kn_b);

    // axial attention (row then col, col accumulates)
    attn_kernel<<<3072, 256, 0, stream>>>(qkv, att, biasT, 0);
    attn_kernel<<<3072, 256, 0, stream>>>(qkv, att, biasT, 1);

    // norm2 + out projection (+gamma_att, +x residual) -> x3 = bf16(inp2)
    statspm_kernel<<<dim3(16, 12, 2), 256, 0, stream>>>(att, part);
    statsfin_kernel<<<6, 256, 0, stream>>>(part, norm2_w, s2);
    stage2_kernel<<<32768, 256, 0, stream>>>(att, s2, xn2);
    gemm_bt<1><<<dim3(256, 6), 256, 0, stream>>>(xn2, woutb, 768, x3, out_b, gamma_att, x, 768);

    // MLP in 4 pixel chunks of 8192
    for (int ch = 0; ch < 4; ch++) {
        gemm_bt<2><<<dim3(64, 24), 256, 0, stream>>>(x3 + (size_t)ch * 8192 * 768, w1t, 768,
                                                     h1b, b1, nullptr, nullptr, 3072);
        gemm_bt<3><<<dim3(64, 6), 256, 0, stream>>>(h1b, w2t, 3072,
                                                    h2 + (size_t)ch * 8192 * 768, b2, nullptr, nullptr, 768);
    }

    // mlp norm + final residual + transpose back to NCHW
    statspm_kernel<<<dim3(16, 12, 2), 256, 0, stream>>>(h2, part);
    statsfin_kernel<<<6, 256, 0, stream>>>(part, mlpnorm_w, s3);
    final_kernel<<<dim3(256, 12, 2), 256, 0, stream>>>(x3, h2, s3, gamma_mlp, out);
}

// Round 2
// 1330.086 us; speedup vs baseline: 1.2002x; 1.2002x over previous
//
#include <hip/hip_runtime.h>
#include <math.h>

// AxialAttentionBlock on gfx950 — round 2.
// Changes vs r1: XOR-swizzled GEMM LDS (kill 16-way bank conflicts), LN(q,k)
// fused into qkv GEMM epilogue, s1/s2 folded into per-batch bf16 weights
// (removes lnqk/stage2/stats1 passes), padded attention LDS, 2-chunk MLP.

typedef unsigned short u16;
typedef short bf16x8 __attribute__((ext_vector_type(8)));
typedef float f32x4 __attribute__((ext_vector_type(4)));

#define DEV static __device__ __forceinline__

DEV u16 f2bf(float f) {
    unsigned int u = __float_as_uint(f);
    u += 0x7fffu + ((u >> 16) & 1u);   // RTN-even
    return (u16)(u >> 16);
}
DEV float bf2f(u16 h) { return __uint_as_float(((unsigned int)h) << 16); }

// async global->LDS, 16B per lane; lds dest is wave-uniform base + lane*16
#define GLD16(gp, lp) __builtin_amdgcn_global_load_lds( \
    (const __attribute__((address_space(1))) unsigned int*)(const void*)(gp), \
    (__attribute__((address_space(3))) unsigned int*)(void*)(lp), 16, 0, 0)

#define MFMA16(a, b, c) __builtin_amdgcn_mfma_f32_16x16x32_bf16((a), (b), (c), 0, 0, 0)

// ---------------------------------------------------------------------------
// prep kernels
// ---------------------------------------------------------------------------
// fp32 [R][C] -> bf16 [C][R]
__global__ void wtrans_kernel(const float* __restrict__ in, u16* __restrict__ out, int R, int C) {
    __shared__ float tile[64][65];
    int r0 = blockIdx.x * 64, c0 = blockIdx.y * 64;
    for (int idx = threadIdx.x; idx < 4096; idx += 256) {
        int rr = idx >> 6, cc = idx & 63;
        tile[rr][cc] = in[(size_t)(r0 + rr) * C + c0 + cc];
    }
    __syncthreads();
    for (int idx = threadIdx.x; idx < 4096; idx += 256) {
        int cc = idx >> 6, rr = idx & 63;
        out[(size_t)(c0 + cc) * R + r0 + rr] = f2bf(tile[rr][cc]);
    }
}

// out[b][i] = bf16(w[i] * s[b*768 + (i % Kd)]) for b=0,1  (fold norm scale into W)
__global__ void wscale_kernel(const float* __restrict__ w, const float* __restrict__ s,
                              u16* __restrict__ out, int NK, int Kd) {
    int i = blockIdx.x * 256 + threadIdx.x;
    if (i < NK) {
        int k = i % Kd;
        float wv = w[i];
        out[i]      = f2bf(wv * s[k]);
        out[NK + i] = f2bf(wv * s[768 + k]);
    }
}

// T5 relative bias table: biasT[head][i][j], L=128
__global__ void bias_kernel(const float* __restrict__ emb, float* __restrict__ biasT) {
    int head = blockIdx.x, i = blockIdx.y, j = threadIdx.x;
    int rp = j - i;
    int ret = rp > 0 ? 16 : 0;
    int arp = rp < 0 ? -rp : rp;
    int bucket;
    if (arp < 8) bucket = ret + arp;
    else {
        int vl = 8 + (int)(logf((float)arp * 0.125f) * (8.0f / logf(16.0f)));
        if (vl > 15) vl = 15;
        bucket = ret + vl;
    }
    biasT[head * 16384 + i * 128 + j] = emb[bucket * 12 + head];
}

// x [B,C,H,W] fp32 -> xn1 bf16 [p, c] transpose + per-(b,c) partial stats
__global__ __launch_bounds__(256) void stage1s_kernel(const float* __restrict__ x,
                                                      u16* __restrict__ xn1,
                                                      float* __restrict__ part) {
    __shared__ float tile[64][65];
    __shared__ float ps[4][64], qs[4][64];
    int hw0 = blockIdx.x * 64, c0 = blockIdx.y * 64, b = blockIdx.z;
    for (int idx = threadIdx.x; idx < 4096; idx += 256) {
        int cc = idx >> 6, ww = idx & 63;
        tile[cc][ww] = x[((size_t)(b * 768 + c0 + cc)) * 16384 + hw0 + ww];
    }
    __syncthreads();
    for (int idx = threadIdx.x; idx < 4096; idx += 256) {
        int ww = idx >> 6, cc = idx & 63;
        xn1[((size_t)(b * 16384 + hw0 + ww)) * 768 + c0 + cc] = f2bf(tile[cc][ww]);
    }
    // stats: wave q sums ww in [q*16, q*16+16) for channel cc = lane
    const int q = threadIdx.x >> 6, cc = threadIdx.x & 63;
    float s = 0.f, sq = 0.f;
#pragma unroll
    for (int w = 0; w < 16; w++) {
        float v = tile[cc][q * 16 + w];
        s += v; sq += v * v;
    }
    ps[q][cc] = s; qs[q][cc] = sq;
    __syncthreads();
    if (threadIdx.x < 64) {
        float S = ps[0][threadIdx.x] + ps[1][threadIdx.x] + ps[2][threadIdx.x] + ps[3][threadIdx.x];
        float Q = qs[0][threadIdx.x] + qs[1][threadIdx.x] + qs[2][threadIdx.x] + qs[3][threadIdx.x];
        size_t idx = ((size_t)(b * 768 + c0 + threadIdx.x) * 256 + blockIdx.x) * 2;
        part[idx] = S;
        part[idx + 1] = Q;
    }
}

// finalize: sc[b*768+c] = w[c] / (std + 1e-8), std unbiased over 16384
__global__ void statsfin_kernel(const float* __restrict__ part, const float* __restrict__ w,
                                float* __restrict__ sc, int npart) {
    int i = blockIdx.x * 256 + threadIdx.x;   // 0..1535 = b*768+c
    if (i < 1536) {
        float S = 0.f, Q = 0.f;
        for (int k = 0; k < npart; k++) { S += part[(i * npart + k) * 2]; Q += part[(i * npart + k) * 2 + 1]; }
        float var = (Q - S * S * (1.0f / 16384.0f)) * (1.0f / 16383.0f);
        sc[i] = w[i % 768] / (sqrtf(var) + 1e-8f);
    }
}

// ---------------------------------------------------------------------------
// MFMA GEMM: C[M,N] = A[M,K] * Bw[N,K]^T (+epilogue); 128x128 tile, BK=64.
// LDS XOR-swizzle: lane fetches global chunk ((lane&7)^srow); read back at
// chunk (gc ^ (row&7)) -> 2-way conflicts only.
// MODE 0: qkv proj; fused LayerNorm over each 64-col head slice for q,k groups
// MODE 1: outb = bf16((acc+bias)*gamma[col] + x[b,col,hw])  (out proj + residual)
// MODE 2: outb = bf16(gelu(acc + bias))                     (mlp1)
// MODE 3: outb = bf16(acc + bias)                           (mlp2)
// ---------------------------------------------------------------------------
template <int MODE>
__global__ __launch_bounds__(256) void gemm_bt(const u16* __restrict__ A,
                                               const u16* __restrict__ Bw, int K,
                                               u16* __restrict__ outb,
                                               const float* __restrict__ bias,
                                               const float* __restrict__ gamma,
                                               const float* __restrict__ xres, int ldc,
                                               size_t bstride,
                                               const float* __restrict__ lnw_q,
                                               const float* __restrict__ lnb_q,
                                               const float* __restrict__ lnw_k,
                                               const float* __restrict__ lnb_k) {
    __shared__ __align__(16) u16 As[8192];
    __shared__ __align__(16) u16 Bs[8192];
    const int tid = threadIdx.x;
    const int wave = tid >> 6, lane = tid & 63;
    const int ln = lane & 15, lq = lane >> 4;
    const int m0 = blockIdx.x * 128, n0 = blockIdx.y * 128;
    const int wm = (wave >> 1) * 64, wn = (wave & 1) * 64;
    const u16* Ag = A + (size_t)m0 * K;
    const u16* Bg = Bw + (size_t)(m0 >> 14) * bstride + (size_t)n0 * K;
    const int srow = lane >> 3;                       // 0..7
    const int scol = ((lane & 7) ^ srow) * 8;         // XOR-swizzled fetch column
    f32x4 acc[4][4] = {};

    for (int k0 = 0; k0 < K; k0 += 64) {
        if (k0) __syncthreads();
#pragma unroll
        for (int r = 0; r < 4; r++) {
            int s = r * 4 + wave;                 // 0..15, wave-uniform
            int row = s * 8 + srow;               // 0..127
            GLD16(Ag + (size_t)row * K + k0 + scol, As + s * 512);
            GLD16(Bg + (size_t)row * K + k0 + scol, Bs + s * 512);
        }
        __syncthreads();
#pragma unroll
        for (int ks = 0; ks < 64; ks += 32) {
            // swizzled read offset: chunk (ks/8 + lq) ^ (row&7), row&7 == ln&7
            const int koS = ((((ks >> 3) + lq) ^ (ln & 7)) << 3);
            bf16x8 af[4], bfr[4];
#pragma unroll
            for (int i = 0; i < 4; i++) af[i] = *(const bf16x8*)&As[(wm + i * 16 + ln) * 64 + koS];
#pragma unroll
            for (int j = 0; j < 4; j++) bfr[j] = *(const bf16x8*)&Bs[(wn + j * 16 + ln) * 64 + koS];
#pragma unroll
            for (int i = 0; i < 4; i++)
#pragma unroll
                for (int j = 0; j < 4; j++)
                    acc[i][j] = MFMA16(af[i], bfr[j], acc[i][j]);
        }
    }

    if (MODE == 0) {
        // fused LayerNorm for q/k 64-col head slices; col group is wave-uniform
        const int g3 = ((unsigned)(n0 + wn) >> 6) % 3;   // 0=q 1=k 2=v
        float bcol[4], wv[4], bvv[4];
#pragma unroll
        for (int j = 0; j < 4; j++) bcol[j] = bias[n0 + wn + j * 16 + ln];
        if (g3 == 0) {
#pragma unroll
            for (int j = 0; j < 4; j++) { wv[j] = lnw_q[j * 16 + ln]; bvv[j] = lnb_q[j * 16 + ln]; }
        } else if (g3 == 1) {
#pragma unroll
            for (int j = 0; j < 4; j++) { wv[j] = lnw_k[j * 16 + ln]; bvv[j] = lnb_k[j * 16 + ln]; }
        }
#pragma unroll
        for (int i = 0; i < 4; i++) {
            const int row0 = m0 + wm + i * 16 + lq * 4;
#pragma unroll
            for (int rg = 0; rg < 4; rg++) {
                float v[4]; float s = 0.f;
#pragma unroll
                for (int j = 0; j < 4; j++) { v[j] = acc[i][j][rg] + bcol[j]; s += v[j]; }
                if (g3 < 2) {
#pragma unroll
                    for (int d = 1; d < 16; d <<= 1) s += __shfl_xor(s, d);
                    const float mean = s * (1.0f / 64.0f);
                    float q2 = 0.f;
#pragma unroll
                    for (int j = 0; j < 4; j++) { float dv = v[j] - mean; q2 += dv * dv; }
#pragma unroll
                    for (int d = 1; d < 16; d <<= 1) q2 += __shfl_xor(q2, d);
                    const float rstd = rsqrtf(q2 * (1.0f / 64.0f) + 1e-5f);
#pragma unroll
                    for (int j = 0; j < 4; j++) v[j] = (v[j] - mean) * rstd * wv[j] + bvv[j];
                }
#pragma unroll
                for (int j = 0; j < 4; j++)
                    outb[(size_t)(row0 + rg) * ldc + n0 + wn + j * 16 + ln] = f2bf(v[j]);
            }
        }
        return;
    }

#pragma unroll
    for (int i = 0; i < 4; i++) {
        const int row0 = m0 + wm + i * 16 + lq * 4;
#pragma unroll
        for (int j = 0; j < 4; j++) {
            const int col = n0 + wn + j * 16 + ln;
            const float bv = bias[col];
            if (MODE == 1) {
                const f32x4 xv = *(const f32x4*)&xres[((size_t)(row0 >> 14) * 768 + col) * 16384 + (row0 & 16383)];
                const float gv = gamma[col];
#pragma unroll
                for (int rg = 0; rg < 4; rg++) {
                    float val = (acc[i][j][rg] + bv) * gv + xv[rg];
                    outb[(size_t)(row0 + rg) * ldc + col] = f2bf(val);
                }
            } else if (MODE == 2) {
#pragma unroll
                for (int rg = 0; rg < 4; rg++) {
                    float val = acc[i][j][rg] + bv;
                    val = 0.5f * val * (1.0f + erff(val * 0.70710678f));
                    outb[(size_t)(row0 + rg) * ldc + col] = f2bf(val);
                }
            } else {
#pragma unroll
                for (int rg = 0; rg < 4; rg++)
                    outb[(size_t)(row0 + rg) * ldc + col] = f2bf(acc[i][j][rg] + bv);
            }
        }
    }
}

// ---------------------------------------------------------------------------
// axial attention, one block per (b, pos, head); L=128, hd=64
// mode 0 (row, seq along W): att = 0.5*O ; mode 1 (col, seq along H): att += 0.5*O
// LDS rows padded (Q/K stride 72, Vt/P stride 136) -> 2-way conflicts only.
// ---------------------------------------------------------------------------
__global__ __launch_bounds__(256) void attn_kernel(const u16* __restrict__ qkv,
                                                   u16* __restrict__ att,
                                                   const float* __restrict__ biasT,
                                                   const int mode) {
    __shared__ __align__(16) u16 sh[27136];   // 54,272 B -> 3 blocks/CU
    u16* Qs = sh;             // [128][72]
    u16* Ks = sh + 9216;      // [128][72]
    u16* Vt = sh + 18432;     // [64][136] (transposed)
    u16* Ps = sh;             // [128][136] overlays Q+K after barrier

    const int t = threadIdx.x, lane = t & 63, wave = t >> 6;
    const int ln = lane & 15, lq = lane >> 4;
    const int head = blockIdx.x % 12;
    const int bp = blockIdx.x / 12;
    const int pos = bp & 127, b = bp >> 7;

    for (int idx = t; idx < 2048; idx += 256) {
        const int i = idx >> 4, c4 = (idx & 15) * 4;
        const size_t p = (mode == 0) ? (size_t)(b * 16384 + pos * 128 + i)
                                     : (size_t)(b * 16384 + i * 128 + pos);
        const u16* src = qkv + p * 2304 + head * 192;
        union { uint2 u; u16 us[4]; } vv;
        *(uint2*)&Qs[i * 72 + c4] = *(const uint2*)(src + c4);
        *(uint2*)&Ks[i * 72 + c4] = *(const uint2*)(src + 64 + c4);
        vv.u = *(const uint2*)(src + 128 + c4);
#pragma unroll
        for (int q = 0; q < 4; q++) Vt[(c4 + q) * 136 + i] = vv.us[q];
    }
    __syncthreads();

    const int wr = wave * 32;
    f32x4 S[2][8] = {};
#pragma unroll
    for (int ks = 0; ks < 64; ks += 32) {
        const int ko = ks + lq * 8;
        bf16x8 aq[2];
#pragma unroll
        for (int i = 0; i < 2; i++) aq[i] = *(const bf16x8*)&Qs[(wr + i * 16 + ln) * 72 + ko];
#pragma unroll
        for (int j = 0; j < 8; j++) {
            const bf16x8 bk = *(const bf16x8*)&Ks[(j * 16 + ln) * 72 + ko];
            S[0][j] = MFMA16(aq[0], bk, S[0][j]);
            S[1][j] = MFMA16(aq[1], bk, S[1][j]);
        }
    }
    __syncthreads();   // all waves done reading Q/K before Ps overlays them

    float rowsum[2][4];
    const float* bp2 = biasT + head * 16384;
#pragma unroll
    for (int i = 0; i < 2; i++) {
#pragma unroll
        for (int rg = 0; rg < 4; rg++) {
            const int r = wr + i * 16 + lq * 4 + rg;
            float v[8];
            float mx = -1e30f;
#pragma unroll
            for (int j = 0; j < 8; j++) {
                v[j] = S[i][j][rg] * 0.125f + bp2[r * 128 + j * 16 + ln];
                mx = fmaxf(mx, v[j]);
            }
#pragma unroll
            for (int d = 1; d < 16; d <<= 1) mx = fmaxf(mx, __shfl_xor(mx, d));
            float sm = 0.f;
#pragma unroll
            for (int j = 0; j < 8; j++) { v[j] = __expf(v[j] - mx); sm += v[j]; }
#pragma unroll
            for (int d = 1; d < 16; d <<= 1) sm += __shfl_xor(sm, d);
            rowsum[i][rg] = sm;
#pragma unroll
            for (int j = 0; j < 8; j++) Ps[r * 136 + j * 16 + ln] = f2bf(v[j]);
        }
    }
    __syncthreads();

    f32x4 O[2][4] = {};
#pragma unroll
    for (int ks = 0; ks < 128; ks += 32) {
        const int ko = ks + lq * 8;
        bf16x8 ap[2];
#pragma unroll
        for (int i = 0; i < 2; i++) ap[i] = *(const bf16x8*)&Ps[(wr + i * 16 + ln) * 136 + ko];
#pragma unroll
        for (int j = 0; j < 4; j++) {
            const bf16x8 bv = *(const bf16x8*)&Vt[(j * 16 + ln) * 136 + ko];
            O[0][j] = MFMA16(ap[0], bv, O[0][j]);
            O[1][j] = MFMA16(ap[1], bv, O[1][j]);
        }
    }

#pragma unroll
    for (int i = 0; i < 2; i++) {
#pragma unroll
        for (int j = 0; j < 4; j++) {
#pragma unroll
            for (int rg = 0; rg < 4; rg++) {
                const int r = wr + i * 16 + lq * 4 + rg;
                const int d = j * 16 + ln;
                const float val = O[i][j][rg] / rowsum[i][rg] * 0.5f;
                const size_t p = (mode == 0) ? (size_t)(b * 16384 + pos * 128 + r)
                                             : (size_t)(b * 16384 + r * 128 + pos);
                const size_t a = p * 768 + head * 64 + d;
                if (mode == 0) att[a] = f2bf(val);
                else           att[a] = f2bf(bf2f(att[a]) + val);
            }
        }
    }
}

// ---------------------------------------------------------------------------
// per-(b,c) partial stats for pixel-major bf16 [p, 768]
// ---------------------------------------------------------------------------
__global__ __launch_bounds__(256) void statspm_kernel(const u16* __restrict__ in,
                                                      float* __restrict__ part) {
    const int c = blockIdx.y * 64 + (threadIdx.x & 63);
    const int g = threadIdx.x >> 6;
    const int b = blockIdx.z;
    const int rend = blockIdx.x * 1024 + 1024;
    float s = 0.f, sq = 0.f;
    for (int r = blockIdx.x * 1024 + g; r < rend; r += 4) {
        float v = bf2f(in[((size_t)(b * 16384 + r)) * 768 + c]);
        s += v; sq += v * v;
    }
    __shared__ float ls[4][64], lqq[4][64];
    ls[g][threadIdx.x & 63] = s;
    lqq[g][threadIdx.x & 63] = sq;
    __syncthreads();
    if (threadIdx.x < 64) {
        float S = ls[0][threadIdx.x] + ls[1][threadIdx.x] + ls[2][threadIdx.x] + ls[3][threadIdx.x];
        float Q = lqq[0][threadIdx.x] + lqq[1][threadIdx.x] + lqq[2][threadIdx.x] + lqq[3][threadIdx.x];
        size_t idx = ((size_t)(b * 768 + blockIdx.y * 64 + threadIdx.x) * 16 + blockIdx.x) * 2;
        part[idx] = S;
        part[idx + 1] = Q;
    }
}

// out[b,c,hw] = x3[p,c] + gamma_mlp[c]*(h2[p,c]*s3[b,c]); transpose back to NCHW
__global__ __launch_bounds__(256) void final_kernel(const u16* __restrict__ x3,
                                                    const u16* __restrict__ h2,
                                                    const float* __restrict__ s3,
                                                    const float* __restrict__ gmlp,
                                                    float* __restrict__ out) {
    __shared__ float tile[64][65];
    int hw0 = blockIdx.x * 64, c0 = blockIdx.y * 64, b = blockIdx.z;
    for (int idx = threadIdx.x; idx < 4096; idx += 256) {
        int ww = idx >> 6, cc = idx & 63;
        int c = c0 + cc;
        size_t pp = ((size_t)(b * 16384 + hw0 + ww)) * 768 + c;
        tile[ww][cc] = bf2f(x3[pp]) + gmlp[c] * (bf2f(h2[pp]) * s3[b * 768 + c]);
    }
    __syncthreads();
    for (int idx = threadIdx.x; idx < 4096; idx += 256) {
        int cc = idx >> 6, ww = idx & 63;
        out[((size_t)(b * 768 + c0 + cc)) * 16384 + hw0 + ww] = tile[ww][cc];
    }
}

// ---------------------------------------------------------------------------
extern "C" void kernel_launch(void* const* d_in, const int* in_sizes, int n_in,
                              void* d_out, int out_size, void* d_ws, size_t ws_size,
                              hipStream_t stream) {
    (void)in_sizes; (void)n_in; (void)out_size;
    const float* x         = (const float*)d_in[0];
    const float* norm1_w   = (const float*)d_in[2];
    const float* norm2_w   = (const float*)d_in[3];
    const float* mlpnorm_w = (const float*)d_in[4];
    const float* gamma_att = (const float*)d_in[5];
    const float* gamma_mlp = (const float*)d_in[6];
    const float* in_w      = (const float*)d_in[7];
    const float* in_b      = (const float*)d_in[8];
    const float* out_w     = (const float*)d_in[9];
    const float* out_b     = (const float*)d_in[10];
    const float* qn_w      = (const float*)d_in[11];
    const float* qn_b      = (const float*)d_in[12];
    const float* kn_w      = (const float*)d_in[13];
    const float* kn_b      = (const float*)d_in[14];
    const float* emb       = (const float*)d_in[15];
    const float* w1        = (const float*)d_in[16];
    const float* b1        = (const float*)d_in[17];
    const float* w2        = (const float*)d_in[18];
    const float* b2        = (const float*)d_in[19];
    float* out = (float*)d_out;

    char* ws = (char*)d_ws;
    // small/weight regions first
    u16*   winb2  = (u16*)(ws + 0);            // 2 copies x 2304x768 bf16 = 7,077,888
    u16*   woutb2 = (u16*)(ws + 7077888);      // 2 copies x 768x768  bf16 = 2,359,296
    u16*   w1t    = (u16*)(ws + 9437184);      // 4,718,592
    u16*   w2t    = (u16*)(ws + 14155776);     // 4,718,592
    float* biasT  = (float*)(ws + 18874368);   //   786,432
    float* s1     = (float*)(ws + 19660800);   //     6,144
    float* s2     = (float*)(ws + 19666944);
    float* s3     = (float*)(ws + 19673088);
    float* part   = (float*)(ws + 19679232);   // 3,145,728 (stage1s needs 256 partials)
    const size_t base = 22824960;
    // big regions
    u16*   qkv = (u16*)(ws + base);                // 150,994,944
    u16*   x3  = (u16*)(ws + base);                //  50,331,648 (reuse after attn)
    u16*   h2  = (u16*)(ws + base + 50331648);     //  50,331,648 (reuse)
    u16*   h1b = (u16*)(ws + base + 100663296);    // 100,663,296 (qkv part3 + att, both dead)
    u16*   xn1 = (u16*)(ws + base + 150994944);    //  50,331,648
    u16*   att = (u16*)(ws + base + 150994944);    //  (overlays xn1 after qkv gemm)
    if (ws_size < base + 201326592) return;        // 224,151,552 needed

    // weight prep
    wtrans_kernel<<<dim3(12, 48), 256, 0, stream>>>(w1, w1t, 768, 3072);
    wtrans_kernel<<<dim3(48, 12), 256, 0, stream>>>(w2, w2t, 3072, 768);
    bias_kernel<<<dim3(12, 128), 128, 0, stream>>>(emb, biasT);

    // transpose x -> bf16 [p,768] + stats; fold norm1 scale into qkv weights
    stage1s_kernel<<<dim3(256, 12, 2), 256, 0, stream>>>(x, xn1, part);
    statsfin_kernel<<<6, 256, 0, stream>>>(part, norm1_w, s1, 256);
    wscale_kernel<<<6912, 256, 0, stream>>>(in_w, s1, winb2, 2304 * 768, 768);

    // qkv projection with fused LN(q,k) epilogue
    gemm_bt<0><<<dim3(256, 18), 256, 0, stream>>>(xn1, winb2, 768, qkv, in_b, nullptr, nullptr,
                                                  2304, (size_t)2304 * 768, qn_w, qn_b, kn_w, kn_b);

    // axial attention (row then col, col accumulates)
    attn_kernel<<<3072, 256, 0, stream>>>(qkv, att, biasT, 0);
    attn_kernel<<<3072, 256, 0, stream>>>(qkv, att, biasT, 1);

    // norm2 folded into out_w; out projection + gamma_att*.. + x residual -> x3
    statspm_kernel<<<dim3(16, 12, 2), 256, 0, stream>>>(att, part);
    statsfin_kernel<<<6, 256, 0, stream>>>(part, norm2_w, s2, 16);
    wscale_kernel<<<2304, 256, 0, stream>>>(out_w, s2, woutb2, 768 * 768, 768);
    gemm_bt<1><<<dim3(256, 6), 256, 0, stream>>>(att, woutb2, 768, x3, out_b, gamma_att, x,
                                                 768, (size_t)768 * 768, nullptr, nullptr, nullptr, nullptr);

    // MLP in 2 pixel chunks of 16384
    for (int ch = 0; ch < 2; ch++) {
        gemm_bt<2><<<dim3(128, 24), 256, 0, stream>>>(x3 + (size_t)ch * 16384 * 768, w1t, 768,
                                                      h1b, b1, nullptr, nullptr, 3072, 0,
                                                      nullptr, nullptr, nullptr, nullptr);
        gemm_bt<3><<<dim3(128, 6), 256, 0, stream>>>(h1b, w2t, 3072,
                                                     h2 + (size_t)ch * 16384 * 768, b2, nullptr, nullptr,
                                                     768, 0, nullptr, nullptr, nullptr, nullptr);
    }

    // mlp norm + final residual + transpose back to NCHW
    statspm_kernel<<<dim3(16, 12, 2), 256, 0, stream>>>(h2, part);
    statsfin_kernel<<<6, 256, 0, stream>>>(part, mlpnorm_w, s3, 16);
    final_kernel<<<dim3(256, 12, 2), 256, 0, stream>>>(x3, h2, s3, gamma_mlp, out);
}

// Round 3
// 1087.330 us; speedup vs baseline: 1.4682x; 1.2233x over previous
//
#include <hip/hip_runtime.h>
#include <math.h>

// AxialAttentionBlock on gfx950 — round 3.
// Changes vs r2: all four GEMMs moved to MX-fp8 (mfma_scale 16x16x128, unit
// e8m0 scales) at ~2x the bf16 MFMA rate and half the staging bytes.
// Activations feeding GEMMs are fp8 (xn1, att, x3q, h1, h2); residual path
// stays fp32/bf16 (x read fp32 in epilogue, x3 bf16). Attention internals
// unchanged (bf16 MFMA), output written fp8.

typedef unsigned short u16;
typedef unsigned char u8;
typedef short bf16x8 __attribute__((ext_vector_type(8)));
typedef float f32x4 __attribute__((ext_vector_type(4)));
typedef int v4i __attribute__((ext_vector_type(4)));
typedef int v8i __attribute__((ext_vector_type(8)));

#define DEV static __device__ __forceinline__

DEV u16 f2bf(float f) {
    unsigned int u = __float_as_uint(f);
    u += 0x7fffu + ((u >> 16) & 1u);   // RTN-even
    return (u16)(u >> 16);
}
DEV float bf2f(u16 h) { return __uint_as_float(((unsigned int)h) << 16); }
DEV u8 f2fp8(float f) {
    return (u8)(__builtin_amdgcn_cvt_pk_fp8_f32(f, f, 0, false) & 0xff);
}
DEV float fp82f(u8 v) { return __builtin_amdgcn_cvt_f32_fp8((int)v, 0); }

// async global->LDS, 16B per lane; lds dest is wave-uniform base + lane*16
#define GLD16(gp, lp) __builtin_amdgcn_global_load_lds( \
    (const __attribute__((address_space(1))) unsigned int*)(const void*)(gp), \
    (__attribute__((address_space(3))) unsigned int*)(void*)(lp), 16, 0, 0)

#define MFMA16(a, b, c) __builtin_amdgcn_mfma_f32_16x16x32_bf16((a), (b), (c), 0, 0, 0)
// fp8 e4m3 A/B (fmt 0), unit scales (e8m0 127 = 1.0)
#define MFMAF8(a, b, c) __builtin_amdgcn_mfma_scale_f32_16x16x128_f8f6f4( \
    (a), (b), (c), 0, 0, 0, 0x7F7F7F7F, 0, 0x7F7F7F7F)

// ---------------------------------------------------------------------------
// prep kernels
// ---------------------------------------------------------------------------
// fp32 [R][C] -> fp8 [C][R]
__global__ void wtrans8_kernel(const float* __restrict__ in, u8* __restrict__ out, int R, int C) {
    __shared__ float tile[64][65];
    int r0 = blockIdx.x * 64, c0 = blockIdx.y * 64;
    for (int idx = threadIdx.x; idx < 4096; idx += 256) {
        int rr = idx >> 6, cc = idx & 63;
        tile[rr][cc] = in[(size_t)(r0 + rr) * C + c0 + cc];
    }
    __syncthreads();
    for (int idx = threadIdx.x; idx < 4096; idx += 256) {
        int cc = idx >> 6, rr = idx & 63;
        out[(size_t)(c0 + cc) * R + r0 + rr] = f2fp8(tile[rr][cc]);
    }
}

// out[b][i] = fp8(w[i] * s[b*768 + (i % Kd)]) for b=0,1  (fold norm scale into W)
__global__ void wscale8_kernel(const float* __restrict__ w, const float* __restrict__ s,
                               u8* __restrict__ out, int NK, int Kd) {
    int i = blockIdx.x * 256 + threadIdx.x;
    if (i < NK) {
        int k = i % Kd;
        float wv = w[i];
        out[i]      = f2fp8(wv * s[k]);
        out[NK + i] = f2fp8(wv * s[768 + k]);
    }
}

// T5 relative bias table: biasT[head][i][j], L=128
__global__ void bias_kernel(const float* __restrict__ emb, float* __restrict__ biasT) {
    int head = blockIdx.x, i = blockIdx.y, j = threadIdx.x;
    int rp = j - i;
    int ret = rp > 0 ? 16 : 0;
    int arp = rp < 0 ? -rp : rp;
    int bucket;
    if (arp < 8) bucket = ret + arp;
    else {
        int vl = 8 + (int)(logf((float)arp * 0.125f) * (8.0f / logf(16.0f)));
        if (vl > 15) vl = 15;
        bucket = ret + vl;
    }
    biasT[head * 16384 + i * 128 + j] = emb[bucket * 12 + head];
}

// x [B,C,H,W] fp32 -> xn1 fp8 [p, c] transpose + per-(b,c) partial stats
__global__ __launch_bounds__(256) void stage1s_kernel(const float* __restrict__ x,
                                                      u8* __restrict__ xn1,
                                                      float* __restrict__ part) {
    __shared__ float tile[64][65];
    __shared__ float ps[4][64], qs[4][64];
    int hw0 = blockIdx.x * 64, c0 = blockIdx.y * 64, b = blockIdx.z;
    for (int idx = threadIdx.x; idx < 4096; idx += 256) {
        int cc = idx >> 6, ww = idx & 63;
        tile[cc][ww] = x[((size_t)(b * 768 + c0 + cc)) * 16384 + hw0 + ww];
    }
    __syncthreads();
    for (int idx = threadIdx.x; idx < 4096; idx += 256) {
        int ww = idx >> 6, cc = idx & 63;
        xn1[((size_t)(b * 16384 + hw0 + ww)) * 768 + c0 + cc] = f2fp8(tile[cc][ww]);
    }
    const int q = threadIdx.x >> 6, cc = threadIdx.x & 63;
    float s = 0.f, sq = 0.f;
#pragma unroll
    for (int w = 0; w < 16; w++) {
        float v = tile[cc][q * 16 + w];
        s += v; sq += v * v;
    }
    ps[q][cc] = s; qs[q][cc] = sq;
    __syncthreads();
    if (threadIdx.x < 64) {
        float S = ps[0][threadIdx.x] + ps[1][threadIdx.x] + ps[2][threadIdx.x] + ps[3][threadIdx.x];
        float Q = qs[0][threadIdx.x] + qs[1][threadIdx.x] + qs[2][threadIdx.x] + qs[3][threadIdx.x];
        size_t idx = ((size_t)(b * 768 + c0 + threadIdx.x) * 256 + blockIdx.x) * 2;
        part[idx] = S;
        part[idx + 1] = Q;
    }
}

// finalize: sc[b*768+c] = w[c] / (std + 1e-8), std unbiased over 16384
__global__ void statsfin_kernel(const float* __restrict__ part, const float* __restrict__ w,
                                float* __restrict__ sc, int npart) {
    int i = blockIdx.x * 256 + threadIdx.x;   // 0..1535 = b*768+c
    if (i < 1536) {
        float S = 0.f, Q = 0.f;
        for (int k = 0; k < npart; k++) { S += part[(i * npart + k) * 2]; Q += part[(i * npart + k) * 2 + 1]; }
        float var = (Q - S * S * (1.0f / 16384.0f)) * (1.0f / 16383.0f);
        sc[i] = w[i % 768] / (sqrtf(var) + 1e-8f);
    }
}

// ---------------------------------------------------------------------------
// MX-fp8 GEMM: C[M,N] = A[M,K] * Bw[N,K]^T; 128x128 tile, BK=128 (fp8 bytes).
// LDS swizzle at 16B-chunk granularity: chunk c stored at c^(row&7).
// MODE 0: qkv proj -> bf16 out + fused LayerNorm on q/k head slices
// MODE 1: out proj: x3 = bf16((acc+bias)*gamma + x), x3q = fp8(same)
// MODE 2: mlp1: fp8(gelu(acc+bias))
// MODE 3: mlp2: fp8(acc+bias)
// ---------------------------------------------------------------------------
template <int MODE>
__global__ __launch_bounds__(256) void gemm_f8(const u8* __restrict__ A,
                                               const u8* __restrict__ Bw, int K,
                                               u16* __restrict__ outh,
                                               u8* __restrict__ outb,
                                               const float* __restrict__ bias,
                                               const float* __restrict__ gamma,
                                               const float* __restrict__ xres, int ldc,
                                               size_t bstride,
                                               const float* __restrict__ lnw_q,
                                               const float* __restrict__ lnb_q,
                                               const float* __restrict__ lnw_k,
                                               const float* __restrict__ lnb_k) {
    __shared__ __align__(16) u8 As[16384];
    __shared__ __align__(16) u8 Bs[16384];
    const int tid = threadIdx.x;
    const int wave = tid >> 6, lane = tid & 63;
    const int ln = lane & 15, lq = lane >> 4;
    const int m0 = blockIdx.x * 128, n0 = blockIdx.y * 128;
    const int wm = (wave >> 1) * 64, wn = (wave & 1) * 64;
    const u8* Ag = A + (size_t)m0 * K;
    const u8* Bg = Bw + (size_t)(m0 >> 14) * bstride + (size_t)n0 * K;
    const int srow = lane >> 3;                          // 0..7
    const int scol = ((lane & 7) ^ srow) * 16;           // swizzled fetch byte col
    // frag read chunk positions (within a 128B row): want chunks 2lq, 2lq+1
    const int cA = ((2 * lq) ^ (ln & 7)) * 16;
    const int cB = ((2 * lq + 1) ^ (ln & 7)) * 16;
    f32x4 acc[4][4] = {};

    for (int k0 = 0; k0 < K; k0 += 128) {
        if (k0) __syncthreads();
#pragma unroll
        for (int r = 0; r < 4; r++) {
            int s = r * 4 + wave;                 // 0..15, wave-uniform
            int row = s * 8 + srow;               // 0..127
            GLD16(Ag + (size_t)row * K + k0 + scol, As + s * 1024);
            GLD16(Bg + (size_t)row * K + k0 + scol, Bs + s * 1024);
        }
        __syncthreads();
        union { v8i v; v4i h[2]; } af[4], bfr[4];
#pragma unroll
        for (int i = 0; i < 4; i++) {
            const u8* base = &As[(wm + i * 16 + ln) * 128];
            af[i].h[0] = *(const v4i*)(base + cA);
            af[i].h[1] = *(const v4i*)(base + cB);
        }
#pragma unroll
        for (int j = 0; j < 4; j++) {
            const u8* base = &Bs[(wn + j * 16 + ln) * 128];
            bfr[j].h[0] = *(const v4i*)(base + cA);
            bfr[j].h[1] = *(const v4i*)(base + cB);
        }
#pragma unroll
        for (int i = 0; i < 4; i++)
#pragma unroll
            for (int j = 0; j < 4; j++)
                acc[i][j] = MFMAF8(af[i].v, bfr[j].v, acc[i][j]);
    }

    if (MODE == 0) {
        // fused LayerNorm for q/k 64-col head slices; col group is wave-uniform
        const int g3 = ((unsigned)(n0 + wn) >> 6) % 3;   // 0=q 1=k 2=v
        float bcol[4], wv[4], bvv[4];
#pragma unroll
        for (int j = 0; j < 4; j++) bcol[j] = bias[n0 + wn + j * 16 + ln];
        if (g3 == 0) {
#pragma unroll
            for (int j = 0; j < 4; j++) { wv[j] = lnw_q[j * 16 + ln]; bvv[j] = lnb_q[j * 16 + ln]; }
        } else if (g3 == 1) {
#pragma unroll
            for (int j = 0; j < 4; j++) { wv[j] = lnw_k[j * 16 + ln]; bvv[j] = lnb_k[j * 16 + ln]; }
        }
#pragma unroll
        for (int i = 0; i < 4; i++) {
            const int row0 = m0 + wm + i * 16 + lq * 4;
#pragma unroll
            for (int rg = 0; rg < 4; rg++) {
                float v[4]; float s = 0.f;
#pragma unroll
                for (int j = 0; j < 4; j++) { v[j] = acc[i][j][rg] + bcol[j]; s += v[j]; }
                if (g3 < 2) {
#pragma unroll
                    for (int d = 1; d < 16; d <<= 1) s += __shfl_xor(s, d);
                    const float mean = s * (1.0f / 64.0f);
                    float q2 = 0.f;
#pragma unroll
                    for (int j = 0; j < 4; j++) { float dv = v[j] - mean; q2 += dv * dv; }
#pragma unroll
                    for (int d = 1; d < 16; d <<= 1) q2 += __shfl_xor(q2, d);
                    const float rstd = rsqrtf(q2 * (1.0f / 64.0f) + 1e-5f);
#pragma unroll
                    for (int j = 0; j < 4; j++) v[j] = (v[j] - mean) * rstd * wv[j] + bvv[j];
                }
#pragma unroll
                for (int j = 0; j < 4; j++)
                    outh[(size_t)(row0 + rg) * ldc + n0 + wn + j * 16 + ln] = f2bf(v[j]);
            }
        }
        return;
    }

#pragma unroll
    for (int i = 0; i < 4; i++) {
        const int row0 = m0 + wm + i * 16 + lq * 4;
#pragma unroll
        for (int j = 0; j < 4; j++) {
            const int col = n0 + wn + j * 16 + ln;
            const float bv = bias[col];
            if (MODE == 1) {
                const f32x4 xv = *(const f32x4*)&xres[((size_t)(row0 >> 14) * 768 + col) * 16384 + (row0 & 16383)];
                const float gv = gamma[col];
#pragma unroll
                for (int rg = 0; rg < 4; rg++) {
                    float val = (acc[i][j][rg] + bv) * gv + xv[rg];
                    outh[(size_t)(row0 + rg) * ldc + col] = f2bf(val);
                    outb[(size_t)(row0 + rg) * ldc + col] = f2fp8(val);
                }
            } else if (MODE == 2) {
#pragma unroll
                for (int rg = 0; rg < 4; rg++) {
                    float val = acc[i][j][rg] + bv;
                    val = 0.5f * val * (1.0f + erff(val * 0.70710678f));
                    outb[(size_t)(row0 + rg) * ldc + col] = f2fp8(val);
                }
            } else {
#pragma unroll
                for (int rg = 0; rg < 4; rg++)
                    outb[(size_t)(row0 + rg) * ldc + col] = f2fp8(acc[i][j][rg] + bv);
            }
        }
    }
}

// ---------------------------------------------------------------------------
// axial attention, one block per (b, pos, head); L=128, hd=64; bf16 MFMA.
// mode 0 (row): att = fp8(0.5*O) ; mode 1 (col): att = fp8(att + 0.5*O)
// ---------------------------------------------------------------------------
__global__ __launch_bounds__(256) void attn_kernel(const u16* __restrict__ qkv,
                                                   u8* __restrict__ att,
                                                   const float* __restrict__ biasT,
                                                   const int mode) {
    __shared__ __align__(16) u16 sh[27136];   // 54,272 B
    u16* Qs = sh;             // [128][72]
    u16* Ks = sh + 9216;      // [128][72]
    u16* Vt = sh + 18432;     // [64][136] (transposed)
    u16* Ps = sh;             // [128][136] overlays Q+K after barrier

    const int t = threadIdx.x, lane = t & 63, wave = t >> 6;
    const int ln = lane & 15, lq = lane >> 4;
    const int head = blockIdx.x % 12;
    const int bp = blockIdx.x / 12;
    const int pos = bp & 127, b = bp >> 7;

    for (int idx = t; idx < 2048; idx += 256) {
        const int i = idx >> 4, c4 = (idx & 15) * 4;
        const size_t p = (mode == 0) ? (size_t)(b * 16384 + pos * 128 + i)
                                     : (size_t)(b * 16384 + i * 128 + pos);
        const u16* src = qkv + p * 2304 + head * 192;
        union { uint2 u; u16 us[4]; } vv;
        *(uint2*)&Qs[i * 72 + c4] = *(const uint2*)(src + c4);
        *(uint2*)&Ks[i * 72 + c4] = *(const uint2*)(src + 64 + c4);
        vv.u = *(const uint2*)(src + 128 + c4);
#pragma unroll
        for (int q = 0; q < 4; q++) Vt[(c4 + q) * 136 + i] = vv.us[q];
    }
    __syncthreads();

    const int wr = wave * 32;
    f32x4 S[2][8] = {};
#pragma unroll
    for (int ks = 0; ks < 64; ks += 32) {
        const int ko = ks + lq * 8;
        bf16x8 aq[2];
#pragma unroll
        for (int i = 0; i < 2; i++) aq[i] = *(const bf16x8*)&Qs[(wr + i * 16 + ln) * 72 + ko];
#pragma unroll
        for (int j = 0; j < 8; j++) {
            const bf16x8 bk = *(const bf16x8*)&Ks[(j * 16 + ln) * 72 + ko];
            S[0][j] = MFMA16(aq[0], bk, S[0][j]);
            S[1][j] = MFMA16(aq[1], bk, S[1][j]);
        }
    }
    __syncthreads();   // all waves done reading Q/K before Ps overlays them

    float rowsum[2][4];
    const float* bp2 = biasT + head * 16384;
#pragma unroll
    for (int i = 0; i < 2; i++) {
#pragma unroll
        for (int rg = 0; rg < 4; rg++) {
            const int r = wr + i * 16 + lq * 4 + rg;
            float v[8];
            float mx = -1e30f;
#pragma unroll
            for (int j = 0; j < 8; j++) {
                v[j] = S[i][j][rg] * 0.125f + bp2[r * 128 + j * 16 + ln];
                mx = fmaxf(mx, v[j]);
            }
#pragma unroll
            for (int d = 1; d < 16; d <<= 1) mx = fmaxf(mx, __shfl_xor(mx, d));
            float sm = 0.f;
#pragma unroll
            for (int j = 0; j < 8; j++) { v[j] = __expf(v[j] - mx); sm += v[j]; }
#pragma unroll
            for (int d = 1; d < 16; d <<= 1) sm += __shfl_xor(sm, d);
            rowsum[i][rg] = sm;
#pragma unroll
            for (int j = 0; j < 8; j++) Ps[r * 136 + j * 16 + ln] = f2bf(v[j]);
        }
    }
    __syncthreads();

    f32x4 O[2][4] = {};
#pragma unroll
    for (int ks = 0; ks < 128; ks += 32) {
        const int ko = ks + lq * 8;
        bf16x8 ap[2];
#pragma unroll
        for (int i = 0; i < 2; i++) ap[i] = *(const bf16x8*)&Ps[(wr + i * 16 + ln) * 136 + ko];
#pragma unroll
        for (int j = 0; j < 4; j++) {
            const bf16x8 bv = *(const bf16x8*)&Vt[(j * 16 + ln) * 136 + ko];
            O[0][j] = MFMA16(ap[0], bv, O[0][j]);
            O[1][j] = MFMA16(ap[1], bv, O[1][j]);
        }
    }

#pragma unroll
    for (int i = 0; i < 2; i++) {
#pragma unroll
        for (int j = 0; j < 4; j++) {
#pragma unroll
            for (int rg = 0; rg < 4; rg++) {
                const int r = wr + i * 16 + lq * 4 + rg;
                const int d = j * 16 + ln;
                const float val = O[i][j][rg] / rowsum[i][rg] * 0.5f;
                const size_t p = (mode == 0) ? (size_t)(b * 16384 + pos * 128 + r)
                                             : (size_t)(b * 16384 + r * 128 + pos);
                const size_t a = p * 768 + head * 64 + d;
                if (mode == 0) att[a] = f2fp8(val);
                else           att[a] = f2fp8(fp82f(att[a]) + val);
            }
        }
    }
}

// ---------------------------------------------------------------------------
// per-(b,c) partial stats for pixel-major fp8 [p, 768]
// ---------------------------------------------------------------------------
__global__ __launch_bounds__(256) void statspm_kernel(const u8* __restrict__ in,
                                                      float* __restrict__ part) {
    const int c = blockIdx.y * 64 + (threadIdx.x & 63);
    const int g = threadIdx.x >> 6;
    const int b = blockIdx.z;
    const int rend = blockIdx.x * 1024 + 1024;
    float s = 0.f, sq = 0.f;
    for (int r = blockIdx.x * 1024 + g; r < rend; r += 4) {
        float v = fp82f(in[((size_t)(b * 16384 + r)) * 768 + c]);
        s += v; sq += v * v;
    }
    __shared__ float ls[4][64], lqq[4][64];
    ls[g][threadIdx.x & 63] = s;
    lqq[g][threadIdx.x & 63] = sq;
    __syncthreads();
    if (threadIdx.x < 64) {
        float S = ls[0][threadIdx.x] + ls[1][threadIdx.x] + ls[2][threadIdx.x] + ls[3][threadIdx.x];
        float Q = lqq[0][threadIdx.x] + lqq[1][threadIdx.x] + lqq[2][threadIdx.x] + lqq[3][threadIdx.x];
        size_t idx = ((size_t)(b * 768 + blockIdx.y * 64 + threadIdx.x) * 16 + blockIdx.x) * 2;
        part[idx] = S;
        part[idx + 1] = Q;
    }
}

// out[b,c,hw] = x3[p,c] + gamma_mlp[c]*(h2[p,c]*s3[b,c]); transpose to NCHW
__global__ __launch_bounds__(256) void final_kernel(const u16* __restrict__ x3,
                                                    const u8* __restrict__ h2,
                                                    const float* __restrict__ s3,
                                                    const float* __restrict__ gmlp,
                                                    float* __restrict__ out) {
    __shared__ float tile[64][65];
    int hw0 = blockIdx.x * 64, c0 = blockIdx.y * 64, b = blockIdx.z;
    for (int idx = threadIdx.x; idx < 4096; idx += 256) {
        int ww = idx >> 6, cc = idx & 63;
        int c = c0 + cc;
        size_t pp = ((size_t)(b * 16384 + hw0 + ww)) * 768 + c;
        tile[ww][cc] = bf2f(x3[pp]) + gmlp[c] * (fp82f(h2[pp]) * s3[b * 768 + c]);
    }
    __syncthreads();
    for (int idx = threadIdx.x; idx < 4096; idx += 256) {
        int cc = idx >> 6, ww = idx & 63;
        out[((size_t)(b * 768 + c0 + cc)) * 16384 + hw0 + ww] = tile[ww][cc];
    }
}

// ---------------------------------------------------------------------------
extern "C" void kernel_launch(void* const* d_in, const int* in_sizes, int n_in,
                              void* d_out, int out_size, void* d_ws, size_t ws_size,
                              hipStream_t stream) {
    (void)in_sizes; (void)n_in; (void)out_size;
    const float* x         = (const float*)d_in[0];
    const float* norm1_w   = (const float*)d_in[2];
    const float* norm2_w   = (const float*)d_in[3];
    const float* mlpnorm_w = (const float*)d_in[4];
    const float* gamma_att = (const float*)d_in[5];
    const float* gamma_mlp = (const float*)d_in[6];
    const float* in_w      = (const float*)d_in[7];
    const float* in_b      = (const float*)d_in[8];
    const float* out_w     = (const float*)d_in[9];
    const float* out_b     = (const float*)d_in[10];
    const float* qn_w      = (const float*)d_in[11];
    const float* qn_b      = (const float*)d_in[12];
    const float* kn_w      = (const float*)d_in[13];
    const float* kn_b      = (const float*)d_in[14];
    const float* emb       = (const float*)d_in[15];
    const float* w1        = (const float*)d_in[16];
    const float* b1        = (const float*)d_in[17];
    const float* w2        = (const float*)d_in[18];
    const float* b2        = (const float*)d_in[19];
    float* out = (float*)d_out;

    char* ws = (char*)d_ws;
    u8*    winb2  = (u8*)(ws + 0);             // 2 x 2304x768 fp8 = 3,538,944
    u8*    woutb2 = (u8*)(ws + 3538944);       // 2 x 768x768 fp8  = 1,179,648
    u8*    w1t    = (u8*)(ws + 4718592);       // [3072][768] fp8  = 2,359,296
    u8*    w2t    = (u8*)(ws + 7077888);       // [768][3072] fp8  = 2,359,296
    float* biasT  = (float*)(ws + 9437184);    //   786,432
    float* s1     = (float*)(ws + 10223616);
    float* s2     = (float*)(ws + 10229760);
    float* s3     = (float*)(ws + 10235904);
    float* part   = (float*)(ws + 10242048);   // 3,145,728
    const size_t base = 13631488;
    u16*   qkv = (u16*)(ws + base);                  // 150,994,944 (dead after attn)
    u16*   x3  = (u16*)(ws + base);                  //  50,331,648 (reuse)
    u8*    x3q = (u8*)(ws + base + 50331648);        //  25,165,824 (reuse)
    u8*    h2  = (u8*)(ws + base + 75497472);        //  25,165,824 (reuse)
    u8*    xn1 = (u8*)(ws + base + 150994944);       //  25,165,824 (dead after qkv gemm)
    u8*    att = (u8*)(ws + base + 150994944);       //  (overlays xn1)
    u8*    h1  = (u8*)(ws + base + 176160768);       //  50,331,648 (chunk buffer)
    if (ws_size < base + 226492416) return;          // 240,123,904 needed

    // weight prep
    wtrans8_kernel<<<dim3(12, 48), 256, 0, stream>>>(w1, w1t, 768, 3072);
    wtrans8_kernel<<<dim3(48, 12), 256, 0, stream>>>(w2, w2t, 3072, 768);
    bias_kernel<<<dim3(12, 128), 128, 0, stream>>>(emb, biasT);

    // transpose x -> fp8 [p,768] + stats; fold norm1 scale into qkv weights
    stage1s_kernel<<<dim3(256, 12, 2), 256, 0, stream>>>(x, xn1, part);
    statsfin_kernel<<<6, 256, 0, stream>>>(part, norm1_w, s1, 256);
    wscale8_kernel<<<6912, 256, 0, stream>>>(in_w, s1, winb2, 2304 * 768, 768);

    // qkv projection (fp8 MX) with fused LN(q,k) epilogue -> bf16 qkv
    gemm_f8<0><<<dim3(256, 18), 256, 0, stream>>>(xn1, winb2, 768, qkv, nullptr, in_b,
                                                  nullptr, nullptr, 2304, (size_t)2304 * 768,
                                                  qn_w, qn_b, kn_w, kn_b);

    // axial attention (row then col, col accumulates) -> fp8 att
    attn_kernel<<<3072, 256, 0, stream>>>(qkv, att, biasT, 0);
    attn_kernel<<<3072, 256, 0, stream>>>(qkv, att, biasT, 1);

    // norm2 folded into out_w; out projection + gamma_att*.. + x residual
    statspm_kernel<<<dim3(16, 12, 2), 256, 0, stream>>>(att, part);
    statsfin_kernel<<<6, 256, 0, stream>>>(part, norm2_w, s2, 16);
    wscale8_kernel<<<2304, 256, 0, stream>>>(out_w, s2, woutb2, 768 * 768, 768);
    gemm_f8<1><<<dim3(256, 6), 256, 0, stream>>>(att, woutb2, 768, x3, x3q, out_b,
                                                 gamma_att, x, 768, (size_t)768 * 768,
                                                 nullptr, nullptr, nullptr, nullptr);

    // MLP in 2 pixel chunks of 16384
    for (int ch = 0; ch < 2; ch++) {
        gemm_f8<2><<<dim3(128, 24), 256, 0, stream>>>(x3q + (size_t)ch * 16384 * 768, w1t, 768,
                                                      nullptr, h1, b1, nullptr, nullptr, 3072, 0,
                                                      nullptr, nullptr, nullptr, nullptr);
        gemm_f8<3><<<dim3(128, 6), 256, 0, stream>>>(h1, w2t, 3072,
                                                     nullptr, h2 + (size_t)ch * 16384 * 768, b2,
                                                     nullptr, nullptr, 768, 0,
                                                     nullptr, nullptr, nullptr, nullptr);
    }

    // mlp norm + final residual + transpose back to NCHW
    statspm_kernel<<<dim3(16, 12, 2), 256, 0, stream>>>(h2, part);
    statsfin_kernel<<<6, 256, 0, stream>>>(part, mlpnorm_w, s3, 16);
    final_kernel<<<dim3(256, 12, 2), 256, 0, stream>>>(x3, h2, s3, gamma_mlp, out);
}